// Round 1
// baseline (231.238 us; speedup 1.0000x reference)
//
#include <hip/hip_runtime.h>

typedef unsigned short u16;
typedef unsigned int   u32;
typedef short  short8 __attribute__((ext_vector_type(8)));
typedef float  f32x4  __attribute__((ext_vector_type(4)));
typedef u16    u16x4  __attribute__((ext_vector_type(4)));

#define NEGMAX 3.402823466e38f

__device__ __forceinline__ u16 f2b(float f) {
    u32 u = __float_as_uint(f);
    u32 r = (u + 0x7fffu + ((u >> 16) & 1u)) >> 16;  // RNE to bf16
    return (u16)r;
}

__device__ __forceinline__ void gload_lds16(const void* g, void* l) {
    __builtin_amdgcn_global_load_lds(
        (const __attribute__((address_space(1))) u32*)g,
        (__attribute__((address_space(3))) u32*)l,
        16, 0, 0);
}

// ---------------- fp32 -> bf16 cast ----------------
__global__ void cvt_bf16(const float* __restrict__ src, u16* __restrict__ dst, int n4) {
    int i = blockIdx.x * blockDim.x + threadIdx.x;
    if (i >= n4) return;
    float4 v = ((const float4*)src)[i];
    u16x4 r = { f2b(v.x), f2b(v.y), f2b(v.z), f2b(v.w) };
    ((u16x4*)dst)[i] = r;
}

// ---------------- C = A @ B^T (A:[M,K], B:[N,K], bf16 in, fp32 acc) ----------------
// 128x128 tile, BK=32, 4 waves (2x2), each wave 64x64 = 4x4 frags of 16x16x32.
__global__ __launch_bounds__(256) void gemm_bt(
    const u16* __restrict__ A, const u16* __restrict__ Bm,
    u16* __restrict__ Cb, float* __restrict__ Cf, const float* __restrict__ bias,
    int M, int N, int K)
{
    __shared__ __align__(16) u16 As[128*32];
    __shared__ __align__(16) u16 Bs[128*32];
    const int t = threadIdx.x;
    const int w = t >> 6, lane = t & 63;
    const int l15 = lane & 15, lg = lane >> 4;
    const int m0 = blockIdx.y * 128, n0 = blockIdx.x * 128;
    const int wr = w >> 1, wc = w & 1;
    f32x4 acc[4][4] = {};

    for (int kt = 0; kt < K; kt += 32) {
        #pragma unroll
        for (int j = 0; j < 2; ++j) {
            const int c   = j*256 + t;
            const int row = c >> 2, colb = (c & 3) * 8;     // 16B per chunk, 4 chunks/row
            gload_lds16(&A [(size_t)(m0+row)*K + kt + colb], &As[(size_t)(j*256 + w*64)*8]);
            gload_lds16(&Bm[(size_t)(n0+row)*K + kt + colb], &Bs[(size_t)(j*256 + w*64)*8]);
        }
        __syncthreads();   // drains vmcnt (global_load_lds) before use
        short8 af[4], bfr[4];
        #pragma unroll
        for (int mi = 0; mi < 4; ++mi)
            af[mi] = *(const short8*)&As[(wr*64 + mi*16 + l15)*32 + lg*8];
        #pragma unroll
        for (int ni = 0; ni < 4; ++ni)
            bfr[ni] = *(const short8*)&Bs[(wc*64 + ni*16 + l15)*32 + lg*8];
        #pragma unroll
        for (int mi = 0; mi < 4; ++mi)
            #pragma unroll
            for (int ni = 0; ni < 4; ++ni)
                acc[mi][ni] = __builtin_amdgcn_mfma_f32_16x16x32_bf16(af[mi], bfr[ni], acc[mi][ni], 0, 0, 0);
        __syncthreads();
    }

    #pragma unroll
    for (int mi = 0; mi < 4; ++mi) {
        #pragma unroll
        for (int ni = 0; ni < 4; ++ni) {
            const int row = m0 + wr*64 + mi*16 + lg*4;
            const int col = n0 + wc*64 + ni*16 + l15;
            if (Cb) {
                #pragma unroll
                for (int r = 0; r < 4; ++r)
                    Cb[(size_t)(row+r)*N + col] = f2b(acc[mi][ni][r]);
            } else {
                const float bv = bias ? bias[col] : 0.f;
                #pragma unroll
                for (int r = 0; r < 4; ++r)
                    Cf[(size_t)(row+r)*N + col] = acc[mi][ni][r] + bv;
            }
        }
    }
}

// ---------------- fused masked flash attention ----------------
// grid: B*H*(N/64) = 1024 blocks, 4 waves; wave w owns q rows q0..q0+15.
// Computes S^T = K @ Q^T per 16kv x 16q frag so kv is the (reg, lane-group) axis.
__global__ __launch_bounds__(256) void attn_fused(
    const u16* __restrict__ qkv,   // [B*N][3072] bf16: q|k|v each 1024 = h*64+d
    const int* __restrict__ mask,  // [B*N] int (bool)
    u16* __restrict__ aout)        // [B*N][1024] bf16
{
    __shared__ __align__(16) u16 Kt[64*72];   // [kv][d], pad 8 -> 144B rows
    __shared__ __align__(16) u16 Vt[64*72];   // [d][kv] transposed
    __shared__ __align__(16) u16 Pl[64*72];   // per-wave 16 rows: [q][kv]
    __shared__ int smask[64];

    const int t = threadIdx.x, w = t >> 6, lane = t & 63;
    const int l15 = lane & 15, lg = lane >> 4;
    const int bx = blockIdx.x;
    const int qt = bx & 31, h = (bx >> 5) & 15, b = bx >> 9;
    const int q0 = qt*64 + w*16;

    const size_t rowQ = (size_t)(b*2048 + q0 + l15);
    const short8 qf0 = *(const short8*)&qkv[rowQ*3072 + h*64 + lg*8];
    const short8 qf1 = *(const short8*)&qkv[rowQ*3072 + h*64 + 32 + lg*8];
    const int mq = mask[b*2048 + q0 + l15];

    float m_run = -NEGMAX, l_run = 0.f;
    f32x4 oacc[4] = {};

    for (int kv0 = 0; kv0 < 2048; kv0 += 64) {
        __syncthreads();
        // stage K [64][64] bf16
        #pragma unroll
        for (int p = 0; p < 2; ++p) {
            int idx = p*256 + t, row = idx >> 3, c8 = idx & 7;
            *(short8*)&Kt[row*72 + c8*8] =
                *(const short8*)&qkv[(size_t)(b*2048 + kv0 + row)*3072 + 1024 + h*64 + c8*8];
        }
        // stage V transposed -> Vt[d][kv]
        #pragma unroll
        for (int p = 0; p < 2; ++p) {
            int row = p*32 + (t >> 3), c8 = t & 7;
            short8 v = *(const short8*)&qkv[(size_t)(b*2048 + kv0 + row)*3072 + 2048 + h*64 + c8*8];
            #pragma unroll
            for (int j = 0; j < 8; ++j) Vt[(c8*8 + j)*72 + row] = (u16)v[j];
        }
        if (t < 64) smask[t] = mask[b*2048 + kv0 + t];
        __syncthreads();

        // S^T frags: row = kv (lg*4+r), col = q (l15)
        f32x4 st[4];
        #pragma unroll
        for (int kvt = 0; kvt < 4; ++kvt) {
            short8 kf0 = *(const short8*)&Kt[(kvt*16 + l15)*72 + lg*8];
            short8 kf1 = *(const short8*)&Kt[(kvt*16 + l15)*72 + 32 + lg*8];
            f32x4 s = {};
            s = __builtin_amdgcn_mfma_f32_16x16x32_bf16(kf0, qf0, s, 0, 0, 0);
            s = __builtin_amdgcn_mfma_f32_16x16x32_bf16(kf1, qf1, s, 0, 0, 0);
            st[kvt] = s;
        }
        // mask + scale + online softmax (stats live at q = l15, replicated x4 groups)
        float pv[16];
        float pmax = -NEGMAX;
        #pragma unroll
        for (int kvt = 0; kvt < 4; ++kvt)
            #pragma unroll
            for (int r = 0; r < 4; ++r) {
                int kvi = kvt*16 + lg*4 + r;
                float lgt = (mq && smask[kvi]) ? st[kvt][r]*0.125f : -NEGMAX;
                pv[kvt*4 + r] = lgt;
                pmax = fmaxf(pmax, lgt);
            }
        pmax = fmaxf(pmax, __shfl_xor(pmax, 16));
        pmax = fmaxf(pmax, __shfl_xor(pmax, 32));
        const float m_new = fmaxf(m_run, pmax);
        const float alpha = __expf(m_run - m_new);
        float rsum = 0.f;
        #pragma unroll
        for (int i = 0; i < 16; ++i) { float p = __expf(pv[i] - m_new); pv[i] = p; rsum += p; }
        rsum += __shfl_xor(rsum, 16);
        rsum += __shfl_xor(rsum, 32);
        l_run = l_run * alpha + rsum;
        m_run = m_new;

        // P -> wave-private LDS as bf16, layout [q][kv]
        #pragma unroll
        for (int kvt = 0; kvt < 4; ++kvt) {
            u32 lo = (u32)f2b(pv[kvt*4+0]) | ((u32)f2b(pv[kvt*4+1]) << 16);
            u32 hi = (u32)f2b(pv[kvt*4+2]) | ((u32)f2b(pv[kvt*4+3]) << 16);
            *(u32*)&Pl[(w*16 + l15)*72 + kvt*16 + lg*4]     = lo;
            *(u32*)&Pl[(w*16 + l15)*72 + kvt*16 + lg*4 + 2] = hi;
        }
        // rescale O (O rows = q = lg*4+r)
        const float a0 = __shfl(alpha, lg*4+0), a1 = __shfl(alpha, lg*4+1),
                    a2 = __shfl(alpha, lg*4+2), a3 = __shfl(alpha, lg*4+3);
        #pragma unroll
        for (int ct = 0; ct < 4; ++ct) {
            oacc[ct][0] *= a0; oacc[ct][1] *= a1; oacc[ct][2] *= a2; oacc[ct][3] *= a3;
        }
        // O += P @ V
        #pragma unroll
        for (int c = 0; c < 2; ++c) {
            short8 pf = *(const short8*)&Pl[(w*16 + l15)*72 + c*32 + lg*8];
            #pragma unroll
            for (int ct = 0; ct < 4; ++ct) {
                short8 vf = *(const short8*)&Vt[(ct*16 + l15)*72 + c*32 + lg*8];
                oacc[ct] = __builtin_amdgcn_mfma_f32_16x16x32_bf16(pf, vf, oacc[ct], 0, 0, 0);
            }
        }
    }

    const float inv = 1.f / l_run;
    const float i0 = __shfl(inv, lg*4+0), i1 = __shfl(inv, lg*4+1),
                i2 = __shfl(inv, lg*4+2), i3 = __shfl(inv, lg*4+3);
    #pragma unroll
    for (int ct = 0; ct < 4; ++ct) {
        const int col = h*64 + ct*16 + l15;
        const size_t r0 = (size_t)(b*2048 + q0 + lg*4);
        aout[(r0+0)*1024 + col] = f2b(oacc[ct][0]*i0);
        aout[(r0+1)*1024 + col] = f2b(oacc[ct][1]*i1);
        aout[(r0+2)*1024 + col] = f2b(oacc[ct][2]*i2);
        aout[(r0+3)*1024 + col] = f2b(oacc[ct][3]*i3);
    }
}

extern "C" void kernel_launch(void* const* d_in, const int* in_sizes, int n_in,
                              void* d_out, int out_size, void* d_ws, size_t ws_size,
                              hipStream_t stream)
{
    (void)in_sizes; (void)n_in; (void)out_size; (void)ws_size;
    const float* x      = (const float*)d_in[0];
    const int*   mask   = (const int*)  d_in[1];
    const float* w_qkv  = (const float*)d_in[2];
    const float* w_proj = (const float*)d_in[3];
    const float* b_proj = (const float*)d_in[4];
    float* out = (float*)d_out;

    const int M = 4096;   // B*N
    const int C = 1024;

    u16* xb   = (u16*)d_ws;                    // M*C
    u16* wqb  = xb   + (size_t)M*C;            // 3C*C
    u16* wpb  = wqb  + (size_t)3*C*C;          // C*C
    u16* qkvb = wpb  + (size_t)C*C;            // M*3C
    u16* aob  = qkvb + (size_t)M*3*C;          // M*C

    cvt_bf16<<<dim3((M*C/4   + 255)/256), 256, 0, stream>>>(x,      xb,  M*C/4);
    cvt_bf16<<<dim3((3*C*C/4 + 255)/256), 256, 0, stream>>>(w_qkv,  wqb, 3*C*C/4);
    cvt_bf16<<<dim3((C*C/4   + 255)/256), 256, 0, stream>>>(w_proj, wpb, C*C/4);

    gemm_bt<<<dim3(3*C/128, M/128), 256, 0, stream>>>(xb, wqb, qkvb, nullptr, nullptr, M, 3*C, C);
    attn_fused<<<dim3(2*16*(2048/64)), 256, 0, stream>>>(qkvb, mask, aob);
    gemm_bt<<<dim3(C/128, M/128), 256, 0, stream>>>(aob, wpb, nullptr, out, b_proj, M, C, C);
}

// Round 2
// 172.062 us; speedup vs baseline: 1.3439x; 1.3439x over previous
//
#include <hip/hip_runtime.h>

typedef unsigned short u16;
typedef unsigned int   u32;
typedef short  short8 __attribute__((ext_vector_type(8)));
typedef float  f32x4  __attribute__((ext_vector_type(4)));
typedef float  f32x16 __attribute__((ext_vector_type(16)));
typedef u16    u16x4  __attribute__((ext_vector_type(4)));

__device__ __forceinline__ u16 f2b(float f) {
    u32 u = __float_as_uint(f);
    u32 r = (u + 0x7fffu + ((u >> 16) & 1u)) >> 16;  // RNE to bf16
    return (u16)r;
}

__device__ __forceinline__ u32 cvtpk(float a, float b) {
    u32 r;
    asm("v_cvt_pk_bf16_f32 %0, %1, %2" : "=v"(r) : "v"(a), "v"(b));
    return r;  // lo = bf16(a), hi = bf16(b)
}

__device__ __forceinline__ void gload_lds16(const void* g, void* l) {
    __builtin_amdgcn_global_load_lds(
        (const __attribute__((address_space(1))) u32*)g,
        (__attribute__((address_space(3))) u32*)l,
        16, 0, 0);
}

// ---------------- fp32 -> bf16 cast ----------------
__global__ void cvt_bf16(const float* __restrict__ src, u16* __restrict__ dst, int n4) {
    int i = blockIdx.x * blockDim.x + threadIdx.x;
    if (i >= n4) return;
    float4 v = ((const float4*)src)[i];
    u16x4 r = { f2b(v.x), f2b(v.y), f2b(v.z), f2b(v.w) };
    ((u16x4*)dst)[i] = r;
}

// ---------------- C = A @ B^T (A:[M,K], B:[N,K], bf16 in, fp32 acc) ----------------
__global__ __launch_bounds__(256) void gemm_bt(
    const u16* __restrict__ A, const u16* __restrict__ Bm,
    u16* __restrict__ Cb, float* __restrict__ Cf, const float* __restrict__ bias,
    int M, int N, int K)
{
    __shared__ __align__(16) u16 As[128*32];
    __shared__ __align__(16) u16 Bs[128*32];
    const int t = threadIdx.x;
    const int w = t >> 6, lane = t & 63;
    const int l15 = lane & 15, lg = lane >> 4;
    const int m0 = blockIdx.y * 128, n0 = blockIdx.x * 128;
    const int wr = w >> 1, wc = w & 1;
    f32x4 acc[4][4] = {};

    for (int kt = 0; kt < K; kt += 32) {
        #pragma unroll
        for (int j = 0; j < 2; ++j) {
            const int c   = j*256 + t;
            const int row = c >> 2, colb = (c & 3) * 8;
            gload_lds16(&A [(size_t)(m0+row)*K + kt + colb], &As[(size_t)(j*256 + w*64)*8]);
            gload_lds16(&Bm[(size_t)(n0+row)*K + kt + colb], &Bs[(size_t)(j*256 + w*64)*8]);
        }
        __syncthreads();
        short8 af[4], bfr[4];
        #pragma unroll
        for (int mi = 0; mi < 4; ++mi)
            af[mi] = *(const short8*)&As[(wr*64 + mi*16 + l15)*32 + lg*8];
        #pragma unroll
        for (int ni = 0; ni < 4; ++ni)
            bfr[ni] = *(const short8*)&Bs[(wc*64 + ni*16 + l15)*32 + lg*8];
        #pragma unroll
        for (int mi = 0; mi < 4; ++mi)
            #pragma unroll
            for (int ni = 0; ni < 4; ++ni)
                acc[mi][ni] = __builtin_amdgcn_mfma_f32_16x16x32_bf16(af[mi], bfr[ni], acc[mi][ni], 0, 0, 0);
        __syncthreads();
    }

    #pragma unroll
    for (int mi = 0; mi < 4; ++mi) {
        #pragma unroll
        for (int ni = 0; ni < 4; ++ni) {
            const int row = m0 + wr*64 + mi*16 + lg*4;
            const int col = n0 + wc*64 + ni*16 + l15;
            if (Cb) {
                #pragma unroll
                for (int r = 0; r < 4; ++r)
                    Cb[(size_t)(row+r)*N + col] = f2b(acc[mi][ni][r]);
            } else {
                const float bv = bias ? bias[col] : 0.f;
                #pragma unroll
                for (int r = 0; r < 4; ++r)
                    Cf[(size_t)(row+r)*N + col] = acc[mi][ni][r] + bv;
            }
        }
    }
}

// ---------------- fused masked flash attention, 32x32 MFMA, in-register P ----------------
// grid 512: 4 waves x 32 q-rows = 128 q/block. KVBLK=64.
// S^T = mfma(K, Q): C row = kv = pat(r)+4*hi, col = q = lane&31.
// P packed in-register (cvt_pk + shfl_xor half swap); V^T in LDS, double-XOR swizzled.
__global__ __launch_bounds__(256) void attn_v2(
    const u16* __restrict__ qkv,   // [B*N][3072] bf16
    const int* __restrict__ mask,  // [B*N]
    u16* __restrict__ aout)        // [B*N][1024] bf16
{
    __shared__ __align__(16) u16 Ks[64*64];   // [kv][d], chunk ^= kv&7
    __shared__ __align__(16) u16 Vt[64*64];   // [d][kv], chunk ^= (d^(d>>3))&7

    const int t = threadIdx.x, w = t >> 6, lane = t & 63;
    const int l31 = lane & 31, hi = lane >> 5;

    // XCD-contiguous work decode: xcd gets 64 consecutive work ids (4 heads)
    const int wid = ((blockIdx.x & 7) << 6) | (blockIdx.x >> 3);
    const int qt = wid & 15, h = (wid >> 4) & 15, b = wid >> 8;
    const int q0 = qt * 128 + w * 32;

    const size_t qrow = (size_t)(b*2048 + q0 + l31);
    short8 qf[4];
    #pragma unroll
    for (int i = 0; i < 4; ++i)
        qf[i] = *(const short8*)&qkv[qrow*3072 + h*64 + i*16 + hi*8];
    const int mq = mask[b*2048 + q0 + l31];

    float m_run = -3e38f, l_run = 0.f;
    f32x16 oacc[2] = {};

    const int vrr = t >> 3, vc8 = t & 7;  // V stage role: rows vrr, vrr+32
    short8 vreg0 = *(const short8*)&qkv[(size_t)(b*2048 +      vrr)*3072 + 2048 + h*64 + vc8*8];
    short8 vreg1 = *(const short8*)&qkv[(size_t)(b*2048 + 32 + vrr)*3072 + 2048 + h*64 + vc8*8];

    for (int kv0 = 0; kv0 < 2048; kv0 += 64) {
        __syncthreads();   // previous tile's compute done; Ks/Vt writable
        // ---- V^T swizzled scalar writes (conflict-free: c8 spreads banks) ----
        #pragma unroll
        for (int p = 0; p < 2; ++p) {
            const int kv = p*32 + vrr;
            const int kvhi = kv >> 3, kvlo = kv & 7;
            const short8 v = p ? vreg1 : vreg0;
            #pragma unroll
            for (int j = 0; j < 8; ++j)
                Vt[(vc8*8 + j)*64 + ((kvhi ^ ((j ^ vc8) & 7)) << 3) + kvlo] = (u16)v[j];
        }
        // ---- K stage: global_load_lds, source pre-swizzled (chunk ^ row&7) ----
        #pragma unroll
        for (int i = 0; i < 2; ++i) {
            const int row = w*16 + i*8 + (lane >> 3);
            const int sc  = (lane & 7) ^ (lane >> 3);
            gload_lds16(&qkv[(size_t)(b*2048 + kv0 + row)*3072 + 1024 + h*64 + sc*8],
                        &Ks[(w*16 + i*8)*64]);
        }
        const unsigned long long bal = __ballot(mask[b*2048 + kv0 + lane] != 0);
        const u32 mwA = (u32)bal, mwB = (u32)(bal >> 32);
        __syncthreads();   // staged data visible (drains vmcnt/lgkm)

        // prefetch next tile's V into regs (overlaps with compute)
        if (kv0 + 64 < 2048) {
            vreg0 = *(const short8*)&qkv[(size_t)(b*2048 + kv0+64 + vrr)*3072 + 2048 + h*64 + vc8*8];
            vreg1 = *(const short8*)&qkv[(size_t)(b*2048 + kv0+96 + vrr)*3072 + 2048 + h*64 + vc8*8];
        }

        // ---- S^T: two 32x32 subtiles, 4 k-steps each ----
        f32x16 st0 = {}, st1 = {};
        #pragma unroll
        for (int kd = 0; kd < 4; ++kd) {
            const int c = (2*kd + hi) ^ (l31 & 7);
            short8 kf0 = *(const short8*)&Ks[ l31      *64 + c*8];
            short8 kf1 = *(const short8*)&Ks[(32 + l31)*64 + c*8];
            st0 = __builtin_amdgcn_mfma_f32_32x32x16_bf16(kf0, qf[kd], st0, 0, 0, 0);
            st1 = __builtin_amdgcn_mfma_f32_32x32x16_bf16(kf1, qf[kd], st1, 0, 0, 0);
        }

        // ---- mask + scale (logits; -3e38 for masked; all-masked row -> uniform) ----
        const u32 km0 = (mq ? mwA : 0u) >> (hi*4);
        const u32 km1 = (mq ? mwB : 0u) >> (hi*4);
        #pragma unroll
        for (int r = 0; r < 16; ++r) {
            const int pat = (r & 3) + 8*(r >> 2);
            const float t0 = ((km0 >> pat) & 1u) ? 0.f : -3e38f;
            const float t1 = ((km1 >> pat) & 1u) ? 0.f : -3e38f;
            st0[r] = fmaf(st0[r], 0.125f, t0);
            st1[r] = fmaf(st1[r], 0.125f, t1);
        }

        // ---- online softmax (stats at lane q = lane&31, replicated across hi) ----
        float pm0 = -3e38f, pm1 = -3e38f, pm2 = -3e38f, pm3 = -3e38f;
        #pragma unroll
        for (int r = 0; r < 16; r += 4) {
            pm0 = fmaxf(pm0, fmaxf(st0[r],   st1[r]));
            pm1 = fmaxf(pm1, fmaxf(st0[r+1], st1[r+1]));
            pm2 = fmaxf(pm2, fmaxf(st0[r+2], st1[r+2]));
            pm3 = fmaxf(pm3, fmaxf(st0[r+3], st1[r+3]));
        }
        float pm = fmaxf(fmaxf(pm0, pm1), fmaxf(pm2, pm3));
        pm = fmaxf(pm, __shfl_xor(pm, 32));
        const float m_new = fmaxf(m_run, pm);
        const float alpha = __expf(m_run - m_new);
        float rs0 = 0.f, rs1 = 0.f;
        #pragma unroll
        for (int r = 0; r < 16; ++r) {
            const float p0 = __expf(st0[r] - m_new);
            const float p1 = __expf(st1[r] - m_new);
            st0[r] = p0; st1[r] = p1;
            rs0 += p0; rs1 += p1;
        }
        float rs = rs0 + rs1;
        rs += __shfl_xor(rs, 32);
        l_run = l_run * alpha + rs;
        m_run = m_new;

        // ---- pack P to bf16 pairs, swap halves (in-register, no LDS) ----
        u32 o_[16], x_[16];
        #pragma unroll
        for (int m = 0; m < 8; ++m) {
            o_[m]     = cvtpk(st0[2*m], st0[2*m+1]);
            o_[8 + m] = cvtpk(st1[2*m], st1[2*m+1]);
        }
        #pragma unroll
        for (int m = 0; m < 16; ++m) x_[m] = (u32)__shfl_xor((int)o_[m], 32);

        // ---- rescale O (O rows = q = pat(r)+4*hi; alpha lives at lane q) ----
        #pragma unroll
        for (int r = 0; r < 16; ++r) {
            const int pat = (r & 3) + 8*(r >> 2);
            const float ar = __shfl(alpha, pat + 4*hi);
            oacc[0][r] *= ar; oacc[1][r] *= ar;
        }

        // ---- PV: O[q][d] += P V, A = packed P, B = V^T rows ----
        #pragma unroll
        for (int kk = 0; kk < 4; ++kk) {
            const int s8 = (kk >> 1) * 8, q4 = (kk & 1) * 4;
            union { u32 u[4]; short8 s; } pa;
            pa.u[0] = hi ? x_[s8+q4+2] : o_[s8+q4];
            pa.u[1] = hi ? x_[s8+q4+3] : o_[s8+q4+1];
            pa.u[2] = hi ? o_[s8+q4+2] : x_[s8+q4];
            pa.u[3] = hi ? o_[s8+q4+3] : x_[s8+q4+1];
            #pragma unroll
            for (int dt = 0; dt < 2; ++dt) {
                const int d = dt*32 + l31;
                const int c = (2*kk + hi) ^ ((d ^ (d >> 3)) & 7);
                short8 vf = *(const short8*)&Vt[d*64 + c*8];
                oacc[dt] = __builtin_amdgcn_mfma_f32_32x32x16_bf16(pa.s, vf, oacc[dt], 0, 0, 0);
            }
        }
    }

    // ---- epilogue ----
    const float inv = 1.f / l_run;
    #pragma unroll
    for (int r = 0; r < 16; ++r) {
        const int pat = (r & 3) + 8*(r >> 2);
        const float ir = __shfl(inv, pat + 4*hi);
        const size_t rowg = (size_t)(b*2048 + q0 + pat + 4*hi);
        aout[rowg*1024 + h*64 +      l31] = f2b(oacc[0][r] * ir);
        aout[rowg*1024 + h*64 + 32 + l31] = f2b(oacc[1][r] * ir);
    }
}

extern "C" void kernel_launch(void* const* d_in, const int* in_sizes, int n_in,
                              void* d_out, int out_size, void* d_ws, size_t ws_size,
                              hipStream_t stream)
{
    (void)in_sizes; (void)n_in; (void)out_size; (void)ws_size;
    const float* x      = (const float*)d_in[0];
    const int*   mask   = (const int*)  d_in[1];
    const float* w_qkv  = (const float*)d_in[2];
    const float* w_proj = (const float*)d_in[3];
    const float* b_proj = (const float*)d_in[4];
    float* out = (float*)d_out;

    const int M = 4096;   // B*N
    const int C = 1024;

    u16* xb   = (u16*)d_ws;                    // M*C
    u16* wqb  = xb   + (size_t)M*C;            // 3C*C
    u16* wpb  = wqb  + (size_t)3*C*C;          // C*C
    u16* qkvb = wpb  + (size_t)C*C;            // M*3C
    u16* aob  = qkvb + (size_t)M*3*C;          // M*C

    cvt_bf16<<<dim3((M*C/4   + 255)/256), 256, 0, stream>>>(x,      xb,  M*C/4);
    cvt_bf16<<<dim3((3*C*C/4 + 255)/256), 256, 0, stream>>>(w_qkv,  wqb, 3*C*C/4);
    cvt_bf16<<<dim3((C*C/4   + 255)/256), 256, 0, stream>>>(w_proj, wpb, C*C/4);

    gemm_bt<<<dim3(3*C/128, M/128), 256, 0, stream>>>(xb, wqb, qkvb, nullptr, nullptr, M, 3*C, C);
    attn_v2<<<dim3(512), 256, 0, stream>>>(qkvb, mask, aob);
    gemm_bt<<<dim3(C/128, M/128), 256, 0, stream>>>(aob, wpb, nullptr, out, b_proj, M, C, C);
}